// Round 6
// baseline (214.941 us; speedup 1.0000x reference)
//
#include <hip/hip_runtime.h>

#define T_LEN      1048576
#define TILE_ROWS  1024
#define NTILES     (T_LEN / TILE_ROWS)    // 1024
#define MAXO       25
#define CLAMP_HI   24.0f
#define BIGF       1e30f

// Saturating-add function f(c) = min(max(c + a, l), h); closed under composition.
struct Trip { float a, l, h; };

__device__ __forceinline__ Trip comb(Trip x, Trip y) {   // apply x first, then y
    Trip r;
    r.a = x.a + y.a;
    r.l = fmaxf(x.l + y.a, y.l);
    r.h = fminf(fmaxf(x.h + y.a, y.l), y.h);
    return r;
}
__device__ __forceinline__ float applyT(Trip p, float c) {
    return fminf(fmaxf(c + p.a, p.l), p.h);
}
__device__ __forceinline__ Trip shflUpTrip(Trip v, int off) {
    Trip r;
    r.a = __shfl_up(v.a, off, 64);
    r.l = __shfl_up(v.l, off, 64);
    r.h = __shfl_up(v.h, off, 64);
    return r;
}

// Single fused kernel with a hand-rolled single grid barrier (arrive counter).
// Topology: scan once -> publish triple -> ONE release fetch_add -> tid0 spins
// (s_sleep backoff) -> redundant 12KB prefix reduction -> softmax -> writes.
// Co-residency by capacity: 30.2KB LDS -> 5 blocks/CU, 1280 slots >= 1024.
// Mechanism (agent-scope atomics + plain payload loads) passed on this harness
// in the round-2 lookback kernel; only the topology changed.
__global__ __launch_bounds__(256)
void k_fused(const int* __restrict__ seq, const float* __restrict__ delta,
             const float* __restrict__ bias, const float* __restrict__ scale,
             unsigned* __restrict__ ctr, float* __restrict__ tri,
             float* __restrict__ out)
{
    __shared__ float tile[256 * MAXO];      // 25600 B staging (one 256-row round)
    __shared__ float c_arr[TILE_ROWS];      // 4096 B per-row counters
    __shared__ Trip  agg[4], agg2[4];
    __shared__ float dl[16], bs[MAXO];

    const int tid = threadIdx.x, lane = tid & 63, wid = tid >> 6;
    const int bid = blockIdx.x;

    if (tid < 16)   dl[tid] = delta[tid];
    if (tid < MAXO) bs[tid] = bias[tid];
    const float sfac = scale[0];

    const int4 s4 = *(const int4*)(seq + bid * TILE_ROWS + tid * 4);
    __syncthreads();

    // ---- phase 1: in-tile scan ONCE (thread owns rows 4*tid .. 4*tid+3) ----
    const Trip t0 = {dl[s4.x], 0.0f, CLAMP_HI};
    const Trip t1 = {dl[s4.y], 0.0f, CLAMP_HI};
    const Trip t2 = {dl[s4.z], 0.0f, CLAMP_HI};
    const Trip t3 = {dl[s4.w], 0.0f, CLAMP_HI};
    Trip inc = comb(comb(t0, t1), comb(t2, t3));
#pragma unroll
    for (int off = 1; off < 64; off <<= 1) {
        Trip o = shflUpTrip(inc, off);
        if (lane >= off) inc = comb(o, inc);
    }
    if (lane == 63) agg[wid] = inc;
    __syncthreads();

    // ---- single grid barrier ------------------------------------------------
    if (tid == 0) {
        const Trip P = comb(comb(agg[0], agg[1]), comb(agg[2], agg[3]));
        tri[3 * bid + 0] = P.a;
        tri[3 * bid + 1] = P.l;
        tri[3 * bid + 2] = P.h;
        __threadfence();                                 // payload before arrive
        __hip_atomic_fetch_add(ctr, 1u, __ATOMIC_RELEASE,
                               __HIP_MEMORY_SCOPE_AGENT);
        int guard = 0;
        while (__hip_atomic_load(ctr, __ATOMIC_ACQUIRE,
                                 __HIP_MEMORY_SCOPE_AGENT) < NTILES) {
            __builtin_amdgcn_s_sleep(2);                 // back off the L2
            if (++guard >= (1 << 24)) break;             // never hang
        }
    }
    __syncthreads();
    // order every lane's tri reads after the barrier (round-2 recipe)
    (void)__hip_atomic_load(ctr, __ATOMIC_ACQUIRE, __HIP_MEMORY_SCOPE_AGENT);

    // ---- phase 2: exclusive grid prefix E = comb of tri[0..bid) ------------
    const float4* p = (const float4*)(tri + tid * 12);   // 4 triples = 48 B
    const float4 f0 = p[0], f1 = p[1], f2 = p[2];
    const Trip ID = {0.0f, -BIGF, BIGF};
    const int base = tid * 4;
    Trip g0 = (base + 0 < bid) ? Trip{f0.x, f0.y, f0.z} : ID;
    Trip g1 = (base + 1 < bid) ? Trip{f0.w, f1.x, f1.y} : ID;
    Trip g2 = (base + 2 < bid) ? Trip{f1.z, f1.w, f2.x} : ID;
    Trip g3 = (base + 3 < bid) ? Trip{f2.y, f2.z, f2.w} : ID;
    Trip ginc = comb(comb(g0, g1), comb(g2, g3));
#pragma unroll
    for (int off = 1; off < 64; off <<= 1) {
        Trip o = shflUpTrip(ginc, off);
        if (lane >= off) ginc = comb(o, ginc);
    }
    if (lane == 63) agg2[wid] = ginc;
    __syncthreads();

    const Trip E = comb(comb(agg2[0], agg2[1]), comb(agg2[2], agg2[3]));

    // ---- per-row counters (t0..t3, inc, agg live across the barrier) -------
    float cb = applyT(E, 0.0f);                        // counter entering tile
    for (int w = 0; w < wid; ++w) cb = applyT(agg[w], cb);
    const Trip prev = shflUpTrip(inc, 1);
    const float c_in = (lane == 0) ? cb : applyT(prev, cb);
    float4 cv;
    cv.x = applyT(t0, c_in);
    cv.y = applyT(t1, cv.x);
    cv.z = applyT(t2, cv.y);
    cv.w = applyT(t3, cv.z);
    *(float4*)(c_arr + 4 * tid) = cv;                  // ds_write_b128
    __syncthreads();

    // ---- softmax + staged write: 4 rounds of 256 rows, wave-local readback --
    const size_t outbase = (size_t)bid * TILE_ROWS * MAXO;
#pragma unroll 1
    for (int r = 0; r < 4; ++r) {
        const float c = c_arr[r * 256 + tid];
        float ev[MAXO];
        float sum = 0.0f;
#pragma unroll
        for (int j = 0; j < MAXO; ++j) {
            ev[j] = __expf(fmaf(-sfac, fabsf((float)j - c), bs[j]));
            sum += ev[j];
        }
        const float rinv = 1.0f / sum;
#pragma unroll
        for (int j = 0; j < MAXO; ++j)                 // stride-25: conflict-free
            tile[tid * MAXO + j] = ev[j] * rinv;

        // each wave streams out only its own 64 rows -> no __syncthreads
        const float4* tp4 = (const float4*)(tile + wid * 64 * MAXO);
        float4* op4 = (float4*)(out + outbase + (size_t)(r * 256 + wid * 64) * MAXO);
#pragma unroll
        for (int k = 0; k < 7; ++k) {
            const int idx = lane + k * 64;
            if (idx < 400) op4[idx] = tp4[idx];        // 6400 B contiguous / wave
        }
    }
}

extern "C" void kernel_launch(void* const* d_in, const int* in_sizes, int n_in,
                              void* d_out, int out_size, void* d_ws, size_t ws_size,
                              hipStream_t stream) {
    const int*   seq   = (const int*)d_in[0];
    const float* delta = (const float*)d_in[1];
    const float* bias  = (const float*)d_in[2];
    const float* scale = (const float*)d_in[3];
    float* out = (float*)d_out;

    unsigned* ctr = (unsigned*)d_ws;                 // 4 B arrive counter
    float*    tri = (float*)((char*)d_ws + 256);     // NTILES*3 floats = 12 KB

    hipMemsetAsync(d_ws, 0, 256, stream);            // zero the counter (ws is poisoned)
    k_fused<<<NTILES, 256, 0, stream>>>(seq, delta, bias, scale, ctr, tri, out);
}

// Round 8
// 126.106 us; speedup vs baseline: 1.7044x; 1.7044x over previous
//
#include <hip/hip_runtime.h>

#define T_LEN      1048576
#define TILE_ROWS  1024
#define NTILES     (T_LEN / TILE_ROWS)    // 1024
#define MAXO       25
#define CLAMP_HI   24.0f
#define BIGF       1e30f

typedef float fvec4 __attribute__((ext_vector_type(4)));  // clang vector: nt-store-able

// Saturating-add function f(c) = min(max(c + a, l), h); closed under composition.
struct Trip { float a, l, h; };

__device__ __forceinline__ Trip comb(Trip x, Trip y) {   // apply x first, then y
    Trip r;
    r.a = x.a + y.a;
    r.l = fmaxf(x.l + y.a, y.l);
    r.h = fminf(fmaxf(x.h + y.a, y.l), y.h);
    return r;
}
__device__ __forceinline__ float applyT(Trip p, float c) {
    return fminf(fmaxf(c + p.a, p.l), p.h);
}
__device__ __forceinline__ Trip shflUpTrip(Trip v, int off) {
    Trip r;
    r.a = __shfl_up(v.a, off, 64);
    r.l = __shfl_up(v.l, off, 64);
    r.h = __shfl_up(v.h, off, 64);
    return r;
}

// NOTE (measured, rounds 2/4/6): intra-kernel grid sync on MI355X costs ~100us
// regardless of mechanism (lookback or arrive-counter) -- agent-scope acquire
// polling invalidates per-XCD caches across the skew window. The kernel
// boundary is the cheap grid barrier (~10us). Keep the two-kernel structure.

// ---------------- K1: per-tile triple (1024 blocks, 256 thr, 1 tile/block) --
__global__ __launch_bounds__(256)
void k1_tile(const int* __restrict__ seq, const float* __restrict__ delta,
             float* __restrict__ tri) {
    __shared__ float dl[16];
    __shared__ Trip agg[4];
    const int tid = threadIdx.x, lane = tid & 63, wid = tid >> 6;
    if (tid < 16) dl[tid] = delta[tid];
    __syncthreads();

    const int4 s4 = *(const int4*)(seq + blockIdx.x * TILE_ROWS + tid * 4);
    Trip t = {dl[s4.x], 0.0f, CLAMP_HI};
    { Trip e = {dl[s4.y], 0.0f, CLAMP_HI}; t = comb(t, e); }
    { Trip e = {dl[s4.z], 0.0f, CLAMP_HI}; t = comb(t, e); }
    { Trip e = {dl[s4.w], 0.0f, CLAMP_HI}; t = comb(t, e); }

#pragma unroll
    for (int off = 1; off < 64; off <<= 1) {
        Trip o = shflUpTrip(t, off);
        if (lane >= off) t = comb(o, t);
    }
    if (lane == 63) agg[wid] = t;
    __syncthreads();

    if (tid == 0) {
        const Trip P = comb(comb(agg[0], agg[1]), comb(agg[2], agg[3]));
        tri[3 * blockIdx.x + 0] = P.a;
        tri[3 * blockIdx.x + 1] = P.l;
        tri[3 * blockIdx.x + 2] = P.h;
    }
}

// ---------------- K2: redundant prefix reduction + tile scan + softmax ------
// Each block reduces tri[0..bid) itself (12 KB, L2-hot) -> no cross-block
// sync, no atomics, no spin. Then row/softmax/write with NONTEMPORAL stores
// (output is write-once, 3x aggregate L2 -> don't allocate).
__global__ __launch_bounds__(256)
void k2_out(const int* __restrict__ seq, const float* __restrict__ delta,
            const float* __restrict__ bias, const float* __restrict__ scale,
            const float* __restrict__ tri, float* __restrict__ out) {
    __shared__ float tile[256 * MAXO];      // 25600 B staging (one 256-row round)
    __shared__ float c_arr[TILE_ROWS];      // 4096 B per-row counters
    __shared__ Trip  agg[4], agg2[4];
    __shared__ float dl[16], bs[MAXO];

    const int tid = threadIdx.x, lane = tid & 63, wid = tid >> 6;
    const int bid = blockIdx.x;

    if (tid < 16)   dl[tid] = delta[tid];
    if (tid < MAXO) bs[tid] = bias[tid];
    const float sfac = scale[0];

    // issue both global loads early so they overlap the scans
    const int4 s4 = *(const int4*)(seq + bid * TILE_ROWS + tid * 4);
    const float4* p = (const float4*)(tri + tid * 12);   // 4 triples = 48 B
    const float4 f0 = p[0], f1 = p[1], f2 = p[2];
    __syncthreads();

    // ---- phase 1: exclusive grid prefix E = comb of tri[0..bid) ------------
    const Trip ID = {0.0f, -BIGF, BIGF};
    const int base = tid * 4;
    Trip g0 = (base + 0 < bid) ? Trip{f0.x, f0.y, f0.z} : ID;
    Trip g1 = (base + 1 < bid) ? Trip{f0.w, f1.x, f1.y} : ID;
    Trip g2 = (base + 2 < bid) ? Trip{f1.z, f1.w, f2.x} : ID;
    Trip g3 = (base + 3 < bid) ? Trip{f2.y, f2.z, f2.w} : ID;
    Trip ginc = comb(comb(g0, g1), comb(g2, g3));
#pragma unroll
    for (int off = 1; off < 64; off <<= 1) {
        Trip o = shflUpTrip(ginc, off);
        if (lane >= off) ginc = comb(o, ginc);
    }
    if (lane == 63) agg2[wid] = ginc;

    // ---- phase 2: in-tile scan (thread owns rows 4*tid .. 4*tid+3) ---------
    const Trip t0 = {dl[s4.x], 0.0f, CLAMP_HI};
    const Trip t1 = {dl[s4.y], 0.0f, CLAMP_HI};
    const Trip t2 = {dl[s4.z], 0.0f, CLAMP_HI};
    const Trip t3 = {dl[s4.w], 0.0f, CLAMP_HI};
    Trip inc = comb(comb(t0, t1), comb(t2, t3));
#pragma unroll
    for (int off = 1; off < 64; off <<= 1) {
        Trip o = shflUpTrip(inc, off);
        if (lane >= off) inc = comb(o, inc);
    }
    if (lane == 63) agg[wid] = inc;
    __syncthreads();

    const Trip E = comb(comb(agg2[0], agg2[1]), comb(agg2[2], agg2[3]));

    // ---- per-row counters ---------------------------------------------------
    float cb = applyT(E, 0.0f);                        // counter entering tile
    for (int w = 0; w < wid; ++w) cb = applyT(agg[w], cb);
    const Trip prev = shflUpTrip(inc, 1);
    const float c_in = (lane == 0) ? cb : applyT(prev, cb);
    float4 cv;
    cv.x = applyT(t0, c_in);
    cv.y = applyT(t1, cv.x);
    cv.z = applyT(t2, cv.y);
    cv.w = applyT(t3, cv.z);
    *(float4*)(c_arr + 4 * tid) = cv;                  // ds_write_b128
    __syncthreads();

    // ---- softmax + staged write: 4 rounds of 256 rows, wave-local readback --
    const size_t outbase = (size_t)bid * TILE_ROWS * MAXO;
#pragma unroll 1
    for (int r = 0; r < 4; ++r) {
        const float c = c_arr[r * 256 + tid];
        float ev[MAXO];
        float sum = 0.0f;
#pragma unroll
        for (int j = 0; j < MAXO; ++j) {
            ev[j] = __expf(fmaf(-sfac, fabsf((float)j - c), bs[j]));
            sum += ev[j];
        }
        const float rinv = 1.0f / sum;
#pragma unroll
        for (int j = 0; j < MAXO; ++j)                 // stride-25: conflict-free
            tile[tid * MAXO + j] = ev[j] * rinv;

        // each wave streams out only its own 64 rows -> no __syncthreads
        const fvec4* tp4 = (const fvec4*)(tile + wid * 64 * MAXO);
        fvec4* op4 = (fvec4*)(out + outbase + (size_t)(r * 256 + wid * 64) * MAXO);
#pragma unroll
        for (int k = 0; k < 7; ++k) {
            const int idx = lane + k * 64;
            if (idx < 400)
                __builtin_nontemporal_store(tp4[idx], op4 + idx);  // nt: bypass L2
        }
    }
}

extern "C" void kernel_launch(void* const* d_in, const int* in_sizes, int n_in,
                              void* d_out, int out_size, void* d_ws, size_t ws_size,
                              hipStream_t stream) {
    const int*   seq   = (const int*)d_in[0];
    const float* delta = (const float*)d_in[1];
    const float* bias  = (const float*)d_in[2];
    const float* scale = (const float*)d_in[3];
    float* out = (float*)d_out;

    float* tri = (float*)d_ws;                     // NTILES*3 floats = 12 KB

    k1_tile<<<NTILES, 256, 0, stream>>>(seq, delta, tri);
    k2_out <<<NTILES, 256, 0, stream>>>(seq, delta, bias, scale, tri, out);
}

// Round 9
// 122.588 us; speedup vs baseline: 1.7534x; 1.0287x over previous
//
#include <hip/hip_runtime.h>

#define T_LEN      1048576
#define TILE_ROWS  1024
#define NTILES     (T_LEN / TILE_ROWS)    // 1024
#define MAXO       25
#define CLAMP_HI   24.0f
#define BIGF       1e30f

// Saturating-add function f(c) = min(max(c + a, l), h); closed under composition.
struct Trip { float a, l, h; };

__device__ __forceinline__ Trip comb(Trip x, Trip y) {   // apply x first, then y
    Trip r;
    r.a = x.a + y.a;
    r.l = fmaxf(x.l + y.a, y.l);
    r.h = fminf(fmaxf(x.h + y.a, y.l), y.h);
    return r;
}
__device__ __forceinline__ float applyT(Trip p, float c) {
    return fminf(fmaxf(c + p.a, p.l), p.h);
}
__device__ __forceinline__ Trip shflUpTrip(Trip v, int off) {
    Trip r;
    r.a = __shfl_up(v.a, off, 64);
    r.l = __shfl_up(v.l, off, 64);
    r.h = __shfl_up(v.h, off, 64);
    return r;
}

// MEASURED session notes:
// - rounds 2/6: intra-kernel grid sync (lookback OR arrive-counter) costs
//   ~100us on MI355X -- agent-scope acquire polling across 8 non-coherent
//   XCD L2s. The kernel boundary IS the cheap grid barrier (~10us).
// - round 8: __builtin_nontemporal_store on the output stream is
//   neutral-to-negative (126.1 vs 120.8us). Plain float4 stores win.

// ---------------- K1: per-tile triple (1024 blocks, 256 thr, 1 tile/block) --
__global__ __launch_bounds__(256)
void k1_tile(const int* __restrict__ seq, const float* __restrict__ delta,
             float* __restrict__ tri) {
    __shared__ float dl[16];
    __shared__ Trip agg[4];
    const int tid = threadIdx.x, lane = tid & 63, wid = tid >> 6;
    if (tid < 16) dl[tid] = delta[tid];
    __syncthreads();

    const int4 s4 = *(const int4*)(seq + blockIdx.x * TILE_ROWS + tid * 4);
    Trip t = {dl[s4.x], 0.0f, CLAMP_HI};
    { Trip e = {dl[s4.y], 0.0f, CLAMP_HI}; t = comb(t, e); }
    { Trip e = {dl[s4.z], 0.0f, CLAMP_HI}; t = comb(t, e); }
    { Trip e = {dl[s4.w], 0.0f, CLAMP_HI}; t = comb(t, e); }

#pragma unroll
    for (int off = 1; off < 64; off <<= 1) {
        Trip o = shflUpTrip(t, off);
        if (lane >= off) t = comb(o, t);
    }
    if (lane == 63) agg[wid] = t;
    __syncthreads();

    if (tid == 0) {
        const Trip P = comb(comb(agg[0], agg[1]), comb(agg[2], agg[3]));
        tri[3 * blockIdx.x + 0] = P.a;
        tri[3 * blockIdx.x + 1] = P.l;
        tri[3 * blockIdx.x + 2] = P.h;
    }
}

// ---------------- K2: redundant prefix reduction + tile scan + softmax ------
// Each block reduces tri[0..bid) itself (12 KB, L2-hot) -> no cross-block
// sync, no atomics, no spin. Then row/softmax/write.
__global__ __launch_bounds__(256)
void k2_out(const int* __restrict__ seq, const float* __restrict__ delta,
            const float* __restrict__ bias, const float* __restrict__ scale,
            const float* __restrict__ tri, float* __restrict__ out) {
    __shared__ float tile[256 * MAXO];      // 25600 B staging (one 256-row round)
    __shared__ float c_arr[TILE_ROWS];      // 4096 B per-row counters
    __shared__ Trip  agg[4], agg2[4];
    __shared__ float dl[16], bs[MAXO];

    const int tid = threadIdx.x, lane = tid & 63, wid = tid >> 6;
    const int bid = blockIdx.x;

    if (tid < 16)   dl[tid] = delta[tid];
    if (tid < MAXO) bs[tid] = bias[tid];
    const float sfac = scale[0];

    // issue both global loads early so they overlap the scans
    const int4 s4 = *(const int4*)(seq + bid * TILE_ROWS + tid * 4);
    const float4* p = (const float4*)(tri + tid * 12);   // 4 triples = 48 B
    const float4 f0 = p[0], f1 = p[1], f2 = p[2];
    __syncthreads();

    // ---- phase 1: exclusive grid prefix E = comb of tri[0..bid) ------------
    const Trip ID = {0.0f, -BIGF, BIGF};
    const int base = tid * 4;
    Trip g0 = (base + 0 < bid) ? Trip{f0.x, f0.y, f0.z} : ID;
    Trip g1 = (base + 1 < bid) ? Trip{f0.w, f1.x, f1.y} : ID;
    Trip g2 = (base + 2 < bid) ? Trip{f1.z, f1.w, f2.x} : ID;
    Trip g3 = (base + 3 < bid) ? Trip{f2.y, f2.z, f2.w} : ID;
    Trip ginc = comb(comb(g0, g1), comb(g2, g3));
#pragma unroll
    for (int off = 1; off < 64; off <<= 1) {
        Trip o = shflUpTrip(ginc, off);
        if (lane >= off) ginc = comb(o, ginc);
    }
    if (lane == 63) agg2[wid] = ginc;

    // ---- phase 2: in-tile scan (thread owns rows 4*tid .. 4*tid+3) ---------
    const Trip t0 = {dl[s4.x], 0.0f, CLAMP_HI};
    const Trip t1 = {dl[s4.y], 0.0f, CLAMP_HI};
    const Trip t2 = {dl[s4.z], 0.0f, CLAMP_HI};
    const Trip t3 = {dl[s4.w], 0.0f, CLAMP_HI};
    Trip inc = comb(comb(t0, t1), comb(t2, t3));
#pragma unroll
    for (int off = 1; off < 64; off <<= 1) {
        Trip o = shflUpTrip(inc, off);
        if (lane >= off) inc = comb(o, inc);
    }
    if (lane == 63) agg[wid] = inc;
    __syncthreads();

    const Trip E = comb(comb(agg2[0], agg2[1]), comb(agg2[2], agg2[3]));

    // ---- per-row counters ---------------------------------------------------
    float cb = applyT(E, 0.0f);                        // counter entering tile
    for (int w = 0; w < wid; ++w) cb = applyT(agg[w], cb);
    const Trip prev = shflUpTrip(inc, 1);
    const float c_in = (lane == 0) ? cb : applyT(prev, cb);
    float4 cv;
    cv.x = applyT(t0, c_in);
    cv.y = applyT(t1, cv.x);
    cv.z = applyT(t2, cv.y);
    cv.w = applyT(t3, cv.z);
    *(float4*)(c_arr + 4 * tid) = cv;                  // ds_write_b128
    __syncthreads();

    // ---- softmax + staged write: 4 rounds of 256 rows, wave-local readback --
    const size_t outbase = (size_t)bid * TILE_ROWS * MAXO;
#pragma unroll 1
    for (int r = 0; r < 4; ++r) {
        const float c = c_arr[r * 256 + tid];
        float ev[MAXO];
        float sum = 0.0f;
#pragma unroll
        for (int j = 0; j < MAXO; ++j) {
            ev[j] = __expf(fmaf(-sfac, fabsf((float)j - c), bs[j]));
            sum += ev[j];
        }
        const float rinv = 1.0f / sum;
#pragma unroll
        for (int j = 0; j < MAXO; ++j)                 // stride-25: bank-conflict-free
            tile[tid * MAXO + j] = ev[j] * rinv;

        // each wave streams out only its own 64 rows -> no __syncthreads
        const float4* tp4 = (const float4*)(tile + wid * 64 * MAXO);
        float4* op4 = (float4*)(out + outbase + (size_t)(r * 256 + wid * 64) * MAXO);
#pragma unroll
        for (int k = 0; k < 7; ++k) {
            const int idx = lane + k * 64;
            if (idx < 400) op4[idx] = tp4[idx];        // 6400 B contiguous / wave
        }
    }
}

extern "C" void kernel_launch(void* const* d_in, const int* in_sizes, int n_in,
                              void* d_out, int out_size, void* d_ws, size_t ws_size,
                              hipStream_t stream) {
    const int*   seq   = (const int*)d_in[0];
    const float* delta = (const float*)d_in[1];
    const float* bias  = (const float*)d_in[2];
    const float* scale = (const float*)d_in[3];
    float* out = (float*)d_out;

    float* tri = (float*)d_ws;                     // NTILES*3 floats = 12 KB

    k1_tile<<<NTILES, 256, 0, stream>>>(seq, delta, tri);
    k2_out <<<NTILES, 256, 0, stream>>>(seq, delta, bias, scale, tri, out);
}